// Round 10
// baseline (213.516 us; speedup 1.0000x reference)
//
#include <hip/hip_runtime.h>

constexpr int N_NODES = 100000;
constexpr int E_EDGES = 1600000;
constexpr int NBLK    = (N_NODES + 1023) / 1024;     // 98 scan blocks

typedef _Float16 f16;
typedef _Float16 f16x2 __attribute__((ext_vector_type(2)));
typedef _Float16 f16x4 __attribute__((ext_vector_type(4)));
typedef _Float16 f16x8 __attribute__((ext_vector_type(8)));
typedef float f32x4 __attribute__((ext_vector_type(4)));

// ---------------------------------------------------------------------------
// MFMA GEMM: h2[N,128](f16) = feat[N,128] @ W[128,128]^T + fused el/er.
// Operand-swapped mfma: lane owns feat-row (l&15), 4 consecutive h-cols.
// ---------------------------------------------------------------------------
__global__ __launch_bounds__(256) void k_gemm(const float* __restrict__ feat,
                                              const float* __restrict__ W,
                                              const float* __restrict__ attn_l,
                                              const float* __restrict__ attn_r,
                                              f16* __restrict__ h2,
                                              float* __restrict__ el,
                                              float* __restrict__ er) {
    __shared__ f16 Wlds[128 * 128];  // 32 KB, row-major [n][k], byte ^= (n&7)<<4
    char* wb = (char*)Wlds;
    const int tid = threadIdx.x;

    {
        int n = tid >> 1;
        int kh = (tid & 1) * 64;
        const float* wsrc = W + n * 128 + kh;
#pragma unroll
        for (int q = 0; q < 8; ++q) {
            float4 u0 = *reinterpret_cast<const float4*>(wsrc + q * 8);
            float4 u1 = *reinterpret_cast<const float4*>(wsrc + q * 8 + 4);
            f16x8 v;
            v[0] = (f16)u0.x; v[1] = (f16)u0.y; v[2] = (f16)u0.z; v[3] = (f16)u0.w;
            v[4] = (f16)u1.x; v[5] = (f16)u1.y; v[6] = (f16)u1.z; v[7] = (f16)u1.w;
            unsigned byte = (unsigned)(n * 256 + kh * 2 + q * 16) ^ ((n & 7) << 4);
            *reinterpret_cast<f16x8*>(wb + byte) = v;
        }
    }
    __syncthreads();

    const int wav  = tid >> 6;
    const int lane = tid & 63;
    const int la = lane & 15;
    const int lb = lane >> 4;
    const int row0w = blockIdx.x * 64 + wav * 16;

    f16x8 ffrag[4];
    {
        int rowA = row0w + la;
        if (rowA >= N_NODES) rowA = N_NODES - 1;
        const float* ap = feat + (size_t)rowA * 128 + lb * 8;
#pragma unroll
        for (int kk = 0; kk < 4; ++kk) {
            float4 u0 = *reinterpret_cast<const float4*>(ap + kk * 32);
            float4 u1 = *reinterpret_cast<const float4*>(ap + kk * 32 + 4);
            f16x8 a;
            a[0] = (f16)u0.x; a[1] = (f16)u0.y; a[2] = (f16)u0.z; a[3] = (f16)u0.w;
            a[4] = (f16)u1.x; a[5] = (f16)u1.y; a[6] = (f16)u1.z; a[7] = (f16)u1.w;
            ffrag[kk] = a;
        }
    }

    f32x4 acc[8];
#pragma unroll
    for (int t = 0; t < 8; ++t) acc[t] = (f32x4){0.f, 0.f, 0.f, 0.f};

#pragma unroll
    for (int t = 0; t < 8; ++t) {
        int wrow = t * 16 + la;
#pragma unroll
        for (int kk = 0; kk < 4; ++kk) {
            unsigned byte = (unsigned)(wrow * 256 + (kk * 32 + lb * 8) * 2) ^ ((wrow & 7) << 4);
            f16x8 b = *reinterpret_cast<const f16x8*>(wb + byte);
            acc[t] = __builtin_amdgcn_mfma_f32_16x16x32_f16(b, ffrag[kk], acc[t], 0, 0, 0);
        }
    }

    const int row = row0w + la;
    const bool ok = row < N_NODES;
    if (ok) {
#pragma unroll
        for (int t = 0; t < 8; ++t) {
            f16x4 hv;
            hv.x = (f16)acc[t][0]; hv.y = (f16)acc[t][1];
            hv.z = (f16)acc[t][2]; hv.w = (f16)acc[t][3];
            *reinterpret_cast<f16x4*>(&h2[(size_t)row * 128 + t * 16 + lb * 4]) = hv;
        }
    }

    float sl[4] = {0.f, 0.f, 0.f, 0.f}, sr[4] = {0.f, 0.f, 0.f, 0.f};
#pragma unroll
    for (int t = 0; t < 8; ++t) {
        float4 alv = reinterpret_cast<const float4*>(attn_l)[t * 4 + lb];
        float4 arv = reinterpret_cast<const float4*>(attn_r)[t * 4 + lb];
        int g = t >> 1;
        sl[g] += acc[t][0] * alv.x + acc[t][1] * alv.y + acc[t][2] * alv.z + acc[t][3] * alv.w;
        sr[g] += acc[t][0] * arv.x + acc[t][1] * arv.y + acc[t][2] * arv.z + acc[t][3] * arv.w;
    }
#pragma unroll
    for (int g = 0; g < 4; ++g) {
        sl[g] += __shfl_xor(sl[g], 16, 64);
        sl[g] += __shfl_xor(sl[g], 32, 64);
        sr[g] += __shfl_xor(sr[g], 16, 64);
        sr[g] += __shfl_xor(sr[g], 32, 64);
    }
    if (lb == 0 && ok) {
        *reinterpret_cast<float4*>(el + (size_t)row * 4) = make_float4(sl[0], sl[1], sl[2], sl[3]);
        *reinterpret_cast<float4*>(er + (size_t)row * 4) = make_float4(sr[0], sr[1], sr[2], sr[3]);
    }
}

// ---------------------------------------------------------------------------
// histogram + rank (zero LDS -> full occupancy)
// ---------------------------------------------------------------------------
__global__ void k_hist(const int4* __restrict__ dst4, int* __restrict__ deg,
                       int4* __restrict__ rank4) {
    int t = blockIdx.x * blockDim.x + threadIdx.x;
    if (t < E_EDGES / 4) {
        int4 d = dst4[t];
        int r0 = atomicAdd(&deg[d.x], 1);
        int r1 = atomicAdd(&deg[d.y], 1);
        int r2 = atomicAdd(&deg[d.z], 1);
        int r3 = atomicAdd(&deg[d.w], 1);
        rank4[t] = make_int4(r0, r1, r2, r3);
    }
}

// ---------------------------------------------------------------------------
// scan over PADDED degrees (3-kernel trio)
// ---------------------------------------------------------------------------
__global__ void k_bsum(const int* __restrict__ deg, int* __restrict__ aux) {
    int tid = threadIdx.x;
    int i0 = blockIdx.x * 1024 + tid * 4;
    int sum = 0;
#pragma unroll
    for (int j = 0; j < 4; ++j)
        if (i0 + j < N_NODES) sum += (deg[i0 + j] + 3) & ~3;
#pragma unroll
    for (int m = 32; m; m >>= 1) sum += __shfl_xor(sum, m, 64);
    __shared__ int wsums[4];
    if ((tid & 63) == 0) wsums[tid >> 6] = sum;
    __syncthreads();
    if (tid == 0) aux[blockIdx.x] = wsums[0] + wsums[1] + wsums[2] + wsums[3];
}

__global__ void k_scanaux(int* __restrict__ aux) {
    __shared__ int s[128];
    int i = threadIdx.x;
    int v = (i < NBLK) ? aux[i] : 0;
    s[i] = v;
    __syncthreads();
#pragma unroll
    for (int d = 1; d < 128; d <<= 1) {
        int t = (i >= d) ? s[i - d] : 0;
        __syncthreads();
        s[i] += t;
        __syncthreads();
    }
    if (i < NBLK) aux[i] = s[i] - v;  // exclusive
}

// bscan: padded prefix -> start; fills pad slots with dummy node; inits dummy
__global__ void k_bscan(const int* __restrict__ deg, const int* __restrict__ aux,
                        int* __restrict__ start, int* __restrict__ ssrc,
                        f16* __restrict__ h2, float* __restrict__ el) {
    if (blockIdx.x == 0 && threadIdx.x == 0) {
        float4 z = make_float4(0.f, 0.f, 0.f, 0.f);
        float4* hrow = reinterpret_cast<float4*>(h2 + (size_t)N_NODES * 128);
#pragma unroll
        for (int q = 0; q < 16; ++q) hrow[q] = z;
        *reinterpret_cast<float4*>(el + (size_t)N_NODES * 4) =
            make_float4(-1e4f, -1e4f, -1e4f, -1e4f);
    }
    int tid = threadIdx.x;
    int lane = tid & 63;
    int wid = tid >> 6;
    int i0 = blockIdx.x * 1024 + tid * 4;
    int v[4], pv[4];
#pragma unroll
    for (int j = 0; j < 4; ++j) {
        v[j]  = (i0 + j < N_NODES) ? deg[i0 + j] : 0;
        pv[j] = (v[j] + 3) & ~3;
    }
    int tsum = pv[0] + pv[1] + pv[2] + pv[3];
    int x = tsum;
#pragma unroll
    for (int d = 1; d < 64; d <<= 1) {
        int t = __shfl_up(x, d, 64);
        if (lane >= d) x += t;
    }
    __shared__ int wsums[4];
    if (lane == 63) wsums[wid] = x;
    __syncthreads();
    int base = aux[blockIdx.x];
#pragma unroll
    for (int w = 0; w < 4; ++w)
        if (w < wid) base += wsums[w];
    int p = base + x - tsum;
#pragma unroll
    for (int j = 0; j < 4; ++j) {
        if (i0 + j < N_NODES) {
            start[i0 + j] = p;
            for (int q = v[j]; q < pv[j]; ++q) ssrc[p + q] = N_NODES;  // pad sentinel
        }
        p += pv[j];
    }
}

// atomic-free scatter, int4-vectorized: slot = start[dst] + rank
__global__ void k_scatter(const int4* __restrict__ src4, const int4* __restrict__ dst4,
                          const int4* __restrict__ rank4, const int* __restrict__ start,
                          int* __restrict__ ssrc) {
    int t = blockIdx.x * blockDim.x + threadIdx.x;
    if (t >= E_EDGES / 4) return;
    int4 s = src4[t];
    int4 d = dst4[t];
    int4 r = rank4[t];
    int p0 = start[d.x] + r.x;
    int p1 = start[d.y] + r.y;
    int p2 = start[d.z] + r.z;
    int p3 = start[d.w] + r.w;
    ssrc[p0] = s.x;
    ssrc[p1] = s.y;
    ssrc[p2] = s.z;
    ssrc[p3] = s.w;
}

// ---------------------------------------------------------------------------
// aggregation: one wave per node; 4 edges/iter in 2 parity halves;
// SOFTWARE-PIPELINED ssrc: int4 s_load of iteration i+1 issues while
// iteration i computes -> current gathers issue from registers at loop top
// (chain depth 2 -> 1 exposed latency). 16B over-read lands in ws slack.
// ---------------------------------------------------------------------------
__global__ __launch_bounds__(128) void k_aggr(const f16* __restrict__ h2,
                                              const float* __restrict__ el,
                                              const float* __restrict__ er,
                                              const int* __restrict__ ssrc,
                                              const int* __restrict__ start,
                                              const int* __restrict__ deg,
                                              float* __restrict__ out) {
    int n = blockIdx.x * 2 + (threadIdx.x >> 6);
    if (n >= N_NODES) return;
    int lane = threadIdx.x & 63;
    int half = lane >> 5;
    int l5 = lane & 31;
    int g = l5 >> 3;
    int d = deg[n];
    int nit = ((d + 3) & ~3) >> 2;                 // int4 iterations
    int s4 = __builtin_amdgcn_readfirstlane(start[n] >> 2);  // int4 index (start%4==0)
    const int4* ssrc4 = reinterpret_cast<const int4*>(ssrc);
    float ern = er[n * 4 + g];

    f16x4 acA = {0, 0, 0, 0}, acB = {0, 0, 0, 0};
    float swA = 0.f, swB = 0.f;

    if (nit > 0) {
        int4 sv = ssrc4[s4];
        for (int it = 0; it < nit; ++it) {
            int4 svn = ssrc4[s4 + it + 1];         // prefetch (slack-safe)

            int nA = half ? sv.y : sv.x;           // edges 4it / 4it+1
            int nB = half ? sv.w : sv.z;           // edges 4it+2 / 4it+3
            float eA = el[(size_t)nA * 4 + g];
            float eB = el[(size_t)nB * 4 + g];
            f16x4 qA = *reinterpret_cast<const f16x4*>(h2 + (size_t)nA * 128 + l5 * 4);
            f16x4 qB = *reinterpret_cast<const f16x4*>(h2 + (size_t)nB * 128 + l5 * 4);

            float xA = eA + ern; xA = fmaxf(xA, 0.2f * xA);
            float xB = eB + ern; xB = fmaxf(xB, 0.2f * xB);
            float wA = __expf(xA);
            float wB = __expf(xB);

            f16 hA = (f16)wA; f16x4 wvA = {hA, hA, hA, hA};
            f16 hB = (f16)wB; f16x4 wvB = {hB, hB, hB, hB};
            acA += wvA * qA; swA += wA;
            acB += wvB * qB; swB += wB;

            sv = svn;
        }
    }

    f16x4 ac = acA + acB;
    float swv = swA + swB;
    // merge the two edge-parity halves
    union { f16x4 v; int u[2]; } uu; uu.v = ac;
    int o0 = __shfl_xor(uu.u[0], 32, 64);
    int o1 = __shfl_xor(uu.u[1], 32, 64);
    union { int u[2]; f16x4 v; } vv; vv.u[0] = o0; vv.u[1] = o1;
    ac += vv.v;
    swv += __shfl_xor(swv, 32, 64);

    float inv = (d > 0) ? 1.0f / swv : 0.0f;
    if (half == 0) {
        float4 o = make_float4((float)ac[0] * inv, (float)ac[1] * inv,
                               (float)ac[2] * inv, (float)ac[3] * inv);
        *reinterpret_cast<float4*>(out + (size_t)n * 128 + l5 * 4) = o;
    }
}

// ---------------------------------------------------------------------------
extern "C" void kernel_launch(void* const* d_in, const int* in_sizes, int n_in,
                              void* d_out, int out_size, void* d_ws, size_t ws_size,
                              hipStream_t stream) {
    const float* feat   = (const float*)d_in[0];
    const float* W      = (const float*)d_in[1];
    const float* attn_l = (const float*)d_in[2];
    const float* attn_r = (const float*)d_in[3];
    const int*   src    = (const int*)d_in[4];
    const int*   dst    = (const int*)d_in[5];
    float* out = (float*)d_out;

    // workspace (~45 MB): h2 has a dummy row; ssrc has padding + prefetch slack
    f16*   h2    = (f16*)d_ws;                                 // (N+8)*128 f16
    float* el    = (float*)(h2 + (size_t)(N_NODES + 8) * 128); // (N+4)*4
    float* er    = el + (size_t)(N_NODES + 4) * 4;             // N*4
    int*   deg   = (int*)(er + (size_t)N_NODES * 4);           // N
    int*   start = deg + N_NODES;                              // N
    int*   rank  = start + N_NODES;                            // E
    int*   ssrc  = rank + E_EDGES;                             // E + 3N (padded)
    int*   aux   = ssrc + E_EDGES + 3 * N_NODES + 64;          // 128

    hipMemsetAsync(deg, 0, N_NODES * sizeof(int), stream);

    k_hist<<<(E_EDGES / 4 + 255) / 256, 256, 0, stream>>>((const int4*)dst, deg, (int4*)rank);
    k_gemm<<<(N_NODES + 63) / 64, 256, 0, stream>>>(feat, W, attn_l, attn_r, h2, el, er);
    k_bsum<<<NBLK, 256, 0, stream>>>(deg, aux);
    k_scanaux<<<1, 128, 0, stream>>>(aux);
    k_bscan<<<NBLK, 256, 0, stream>>>(deg, aux, start, ssrc, h2, el);
    k_scatter<<<(E_EDGES / 4 + 255) / 256, 256, 0, stream>>>(
        (const int4*)src, (const int4*)dst, (const int4*)rank, start, ssrc);
    k_aggr<<<(N_NODES + 1) / 2, 128, 0, stream>>>(h2, el, er, ssrc, start, deg, out);
}

// Round 11
// 187.670 us; speedup vs baseline: 1.1377x; 1.1377x over previous
//
#include <hip/hip_runtime.h>

constexpr int N_NODES = 100000;
constexpr int E_EDGES = 1600000;
constexpr int NBLK    = (N_NODES + 1023) / 1024;     // 98 scan blocks
constexpr int NBLOCKS = (N_NODES + 63) / 64;         // 1563 (= ceil(E/4/256) too)

typedef _Float16 f16;
typedef _Float16 f16x2 __attribute__((ext_vector_type(2)));
typedef _Float16 f16x4 __attribute__((ext_vector_type(4)));
typedef _Float16 f16x8 __attribute__((ext_vector_type(8)));
typedef float f32x4 __attribute__((ext_vector_type(4)));

// ---------------------------------------------------------------------------
// hist phase: 256 int4 edge-slices per block (4 edges/thread)
// ---------------------------------------------------------------------------
__device__ __forceinline__ void hist_phase(int bid, int tid,
                                           const int4* __restrict__ dst4,
                                           int* __restrict__ deg,
                                           int4* __restrict__ rank4) {
    int t = bid * 256 + tid;
    if (t < E_EDGES / 4) {
        int4 d = dst4[t];
        int r0 = atomicAdd(&deg[d.x], 1);
        int r1 = atomicAdd(&deg[d.y], 1);
        int r2 = atomicAdd(&deg[d.z], 1);
        int r3 = atomicAdd(&deg[d.w], 1);
        rank4[t] = make_int4(r0, r1, r2, r3);
    }
}

// ---------------------------------------------------------------------------
// gemm phase: MFMA h2[64 rows] + fused el/er (operand-swapped layout)
// ---------------------------------------------------------------------------
__device__ __forceinline__ void gemm_phase(int bid, int tid, f16* Wlds,
                                           const float* __restrict__ feat,
                                           const float* __restrict__ W,
                                           const float* __restrict__ attn_l,
                                           const float* __restrict__ attn_r,
                                           f16* __restrict__ h2,
                                           float* __restrict__ el,
                                           float* __restrict__ er) {
    char* wb = (char*)Wlds;
    {
        int n = tid >> 1;
        int kh = (tid & 1) * 64;
        const float* wsrc = W + n * 128 + kh;
#pragma unroll
        for (int q = 0; q < 8; ++q) {
            float4 u0 = *reinterpret_cast<const float4*>(wsrc + q * 8);
            float4 u1 = *reinterpret_cast<const float4*>(wsrc + q * 8 + 4);
            f16x8 v;
            v[0] = (f16)u0.x; v[1] = (f16)u0.y; v[2] = (f16)u0.z; v[3] = (f16)u0.w;
            v[4] = (f16)u1.x; v[5] = (f16)u1.y; v[6] = (f16)u1.z; v[7] = (f16)u1.w;
            unsigned byte = (unsigned)(n * 256 + kh * 2 + q * 16) ^ ((n & 7) << 4);
            *reinterpret_cast<f16x8*>(wb + byte) = v;
        }
    }
    __syncthreads();

    const int wav  = tid >> 6;
    const int lane = tid & 63;
    const int la = lane & 15;
    const int lb = lane >> 4;
    const int row0w = bid * 64 + wav * 16;

    f16x8 ffrag[4];
    {
        int rowA = row0w + la;
        if (rowA >= N_NODES) rowA = N_NODES - 1;
        const float* ap = feat + (size_t)rowA * 128 + lb * 8;
#pragma unroll
        for (int kk = 0; kk < 4; ++kk) {
            float4 u0 = *reinterpret_cast<const float4*>(ap + kk * 32);
            float4 u1 = *reinterpret_cast<const float4*>(ap + kk * 32 + 4);
            f16x8 a;
            a[0] = (f16)u0.x; a[1] = (f16)u0.y; a[2] = (f16)u0.z; a[3] = (f16)u0.w;
            a[4] = (f16)u1.x; a[5] = (f16)u1.y; a[6] = (f16)u1.z; a[7] = (f16)u1.w;
            ffrag[kk] = a;
        }
    }

    f32x4 acc[8];
#pragma unroll
    for (int t = 0; t < 8; ++t) acc[t] = (f32x4){0.f, 0.f, 0.f, 0.f};

#pragma unroll
    for (int t = 0; t < 8; ++t) {
        int wrow = t * 16 + la;
#pragma unroll
        for (int kk = 0; kk < 4; ++kk) {
            unsigned byte = (unsigned)(wrow * 256 + (kk * 32 + lb * 8) * 2) ^ ((wrow & 7) << 4);
            f16x8 b = *reinterpret_cast<const f16x8*>(wb + byte);
            acc[t] = __builtin_amdgcn_mfma_f32_16x16x32_f16(b, ffrag[kk], acc[t], 0, 0, 0);
        }
    }

    const int row = row0w + la;
    const bool ok = row < N_NODES;
    if (ok) {
#pragma unroll
        for (int t = 0; t < 8; ++t) {
            f16x4 hv;
            hv.x = (f16)acc[t][0]; hv.y = (f16)acc[t][1];
            hv.z = (f16)acc[t][2]; hv.w = (f16)acc[t][3];
            *reinterpret_cast<f16x4*>(&h2[(size_t)row * 128 + t * 16 + lb * 4]) = hv;
        }
    }

    float sl[4] = {0.f, 0.f, 0.f, 0.f}, sr[4] = {0.f, 0.f, 0.f, 0.f};
#pragma unroll
    for (int t = 0; t < 8; ++t) {
        float4 alv = reinterpret_cast<const float4*>(attn_l)[t * 4 + lb];
        float4 arv = reinterpret_cast<const float4*>(attn_r)[t * 4 + lb];
        int g = t >> 1;
        sl[g] += acc[t][0] * alv.x + acc[t][1] * alv.y + acc[t][2] * alv.z + acc[t][3] * alv.w;
        sr[g] += acc[t][0] * arv.x + acc[t][1] * arv.y + acc[t][2] * arv.z + acc[t][3] * arv.w;
    }
#pragma unroll
    for (int g = 0; g < 4; ++g) {
        sl[g] += __shfl_xor(sl[g], 16, 64);
        sl[g] += __shfl_xor(sl[g], 32, 64);
        sr[g] += __shfl_xor(sr[g], 16, 64);
        sr[g] += __shfl_xor(sr[g], 32, 64);
    }
    if (lb == 0 && ok) {
        *reinterpret_cast<float4*>(el + (size_t)row * 4) = make_float4(sl[0], sl[1], sl[2], sl[3]);
        *reinterpret_cast<float4*>(er + (size_t)row * 4) = make_float4(sr[0], sr[1], sr[2], sr[3]);
    }
}

// ---------------------------------------------------------------------------
// fused gemm+hist, PHASE-STAGGERED: even blocks gemm->hist, odd hist->gemm.
// Guarantees ~half the co-resident blocks per CU are in each phase ->
// atomic-latency phase hides under MFMA/LDS phase.
// ---------------------------------------------------------------------------
__global__ __launch_bounds__(256) void k_gemm_hist(
        const float* __restrict__ feat, const float* __restrict__ W,
        const float* __restrict__ attn_l, const float* __restrict__ attn_r,
        f16* __restrict__ h2, float* __restrict__ el, float* __restrict__ er,
        const int4* __restrict__ dst4, int* __restrict__ deg,
        int4* __restrict__ rank4) {
    __shared__ f16 Wlds[128 * 128];  // 32 KB -> 5 blocks/CU
    const int bid = blockIdx.x;
    const int tid = threadIdx.x;
    if (bid & 1) {
        hist_phase(bid, tid, dst4, deg, rank4);
        gemm_phase(bid, tid, Wlds, feat, W, attn_l, attn_r, h2, el, er);
    } else {
        gemm_phase(bid, tid, Wlds, feat, W, attn_l, attn_r, h2, el, er);
        hist_phase(bid, tid, dst4, deg, rank4);
    }
}

// ---------------------------------------------------------------------------
// scan over PADDED degrees: bsum -> bscan (bscan self-scans aux, no scanaux)
// ---------------------------------------------------------------------------
__global__ void k_bsum(const int* __restrict__ deg, int* __restrict__ aux) {
    int tid = threadIdx.x;
    int i0 = blockIdx.x * 1024 + tid * 4;
    int sum = 0;
#pragma unroll
    for (int j = 0; j < 4; ++j)
        if (i0 + j < N_NODES) sum += (deg[i0 + j] + 3) & ~3;
#pragma unroll
    for (int m = 32; m; m >>= 1) sum += __shfl_xor(sum, m, 64);
    __shared__ int wsums[4];
    if ((tid & 63) == 0) wsums[tid >> 6] = sum;
    __syncthreads();
    if (tid == 0) aux[blockIdx.x] = wsums[0] + wsums[1] + wsums[2] + wsums[3];
}

// bscan: computes own base = sum(aux[j < blockIdx]); padded prefix -> start;
// fills pad sentinels; inits dummy node.
__global__ void k_bscan(const int* __restrict__ deg, const int* __restrict__ aux,
                        int* __restrict__ start, int* __restrict__ ssrc,
                        f16* __restrict__ h2, float* __restrict__ el) {
    if (blockIdx.x == 0 && threadIdx.x == 0) {
        float4 z = make_float4(0.f, 0.f, 0.f, 0.f);
        float4* hrow = reinterpret_cast<float4*>(h2 + (size_t)N_NODES * 128);
#pragma unroll
        for (int q = 0; q < 16; ++q) hrow[q] = z;
        *reinterpret_cast<float4*>(el + (size_t)N_NODES * 4) =
            make_float4(-1e4f, -1e4f, -1e4f, -1e4f);
    }
    int tid = threadIdx.x;
    int lane = tid & 63;
    int wid = tid >> 6;

    // block base: wave 0 reduces aux[j < blockIdx]
    __shared__ int sbase;
    if (tid < 64) {
        int a = 0;
        if (tid < blockIdx.x) a += aux[tid];
        if (tid + 64 < blockIdx.x) a += aux[tid + 64];
#pragma unroll
        for (int m = 32; m; m >>= 1) a += __shfl_xor(a, m, 64);
        if (tid == 0) sbase = a;
    }

    int i0 = blockIdx.x * 1024 + tid * 4;
    int v[4], pv[4];
#pragma unroll
    for (int j = 0; j < 4; ++j) {
        v[j]  = (i0 + j < N_NODES) ? deg[i0 + j] : 0;
        pv[j] = (v[j] + 3) & ~3;
    }
    int tsum = pv[0] + pv[1] + pv[2] + pv[3];
    int x = tsum;
#pragma unroll
    for (int d = 1; d < 64; d <<= 1) {
        int t = __shfl_up(x, d, 64);
        if (lane >= d) x += t;
    }
    __shared__ int wsums[4];
    if (lane == 63) wsums[wid] = x;
    __syncthreads();
    int base = sbase;
#pragma unroll
    for (int w = 0; w < 4; ++w)
        if (w < wid) base += wsums[w];
    int p = base + x - tsum;
#pragma unroll
    for (int j = 0; j < 4; ++j) {
        if (i0 + j < N_NODES) {
            start[i0 + j] = p;
            for (int q = v[j]; q < pv[j]; ++q) ssrc[p + q] = N_NODES;  // pad sentinel
        }
        p += pv[j];
    }
}

// atomic-free scatter, int4-vectorized: slot = start[dst] + rank
__global__ void k_scatter(const int4* __restrict__ src4, const int4* __restrict__ dst4,
                          const int4* __restrict__ rank4, const int* __restrict__ start,
                          int* __restrict__ ssrc) {
    int t = blockIdx.x * blockDim.x + threadIdx.x;
    if (t >= E_EDGES / 4) return;
    int4 s = src4[t];
    int4 d = dst4[t];
    int4 r = rank4[t];
    int p0 = start[d.x] + r.x;
    int p1 = start[d.y] + r.y;
    int p2 = start[d.z] + r.z;
    int p3 = start[d.w] + r.w;
    ssrc[p0] = s.x;
    ssrc[p1] = s.y;
    ssrc[p2] = s.z;
    ssrc[p3] = s.w;
}

// ---------------------------------------------------------------------------
// aggregation (at structural roofline ~74us: 410MB random LLC gather).
// one wave per node; 4 edges/iter in 2 parity halves; pipelined ssrc.
// ---------------------------------------------------------------------------
__global__ __launch_bounds__(128) void k_aggr(const f16* __restrict__ h2,
                                              const float* __restrict__ el,
                                              const float* __restrict__ er,
                                              const int* __restrict__ ssrc,
                                              const int* __restrict__ start,
                                              const int* __restrict__ deg,
                                              float* __restrict__ out) {
    int n = blockIdx.x * 2 + (threadIdx.x >> 6);
    if (n >= N_NODES) return;
    int lane = threadIdx.x & 63;
    int half = lane >> 5;
    int l5 = lane & 31;
    int g = l5 >> 3;
    int d = deg[n];
    int nit = ((d + 3) & ~3) >> 2;
    int s4 = __builtin_amdgcn_readfirstlane(start[n] >> 2);
    const int4* ssrc4 = reinterpret_cast<const int4*>(ssrc);
    float ern = er[n * 4 + g];

    f16x4 acA = {0, 0, 0, 0}, acB = {0, 0, 0, 0};
    float swA = 0.f, swB = 0.f;

    if (nit > 0) {
        int4 sv = ssrc4[s4];
        for (int it = 0; it < nit; ++it) {
            int4 svn = ssrc4[s4 + it + 1];

            int nA = half ? sv.y : sv.x;
            int nB = half ? sv.w : sv.z;
            float eA = el[(size_t)nA * 4 + g];
            float eB = el[(size_t)nB * 4 + g];
            f16x4 qA = *reinterpret_cast<const f16x4*>(h2 + (size_t)nA * 128 + l5 * 4);
            f16x4 qB = *reinterpret_cast<const f16x4*>(h2 + (size_t)nB * 128 + l5 * 4);

            float xA = eA + ern; xA = fmaxf(xA, 0.2f * xA);
            float xB = eB + ern; xB = fmaxf(xB, 0.2f * xB);
            float wA = __expf(xA);
            float wB = __expf(xB);

            f16 hA = (f16)wA; f16x4 wvA = {hA, hA, hA, hA};
            f16 hB = (f16)wB; f16x4 wvB = {hB, hB, hB, hB};
            acA += wvA * qA; swA += wA;
            acB += wvB * qB; swB += wB;

            sv = svn;
        }
    }

    f16x4 ac = acA + acB;
    float swv = swA + swB;
    union { f16x4 v; int u[2]; } uu; uu.v = ac;
    int o0 = __shfl_xor(uu.u[0], 32, 64);
    int o1 = __shfl_xor(uu.u[1], 32, 64);
    union { int u[2]; f16x4 v; } vv; vv.u[0] = o0; vv.u[1] = o1;
    ac += vv.v;
    swv += __shfl_xor(swv, 32, 64);

    float inv = (d > 0) ? 1.0f / swv : 0.0f;
    if (half == 0) {
        float4 o = make_float4((float)ac[0] * inv, (float)ac[1] * inv,
                               (float)ac[2] * inv, (float)ac[3] * inv);
        *reinterpret_cast<float4*>(out + (size_t)n * 128 + l5 * 4) = o;
    }
}

// ---------------------------------------------------------------------------
extern "C" void kernel_launch(void* const* d_in, const int* in_sizes, int n_in,
                              void* d_out, int out_size, void* d_ws, size_t ws_size,
                              hipStream_t stream) {
    const float* feat   = (const float*)d_in[0];
    const float* W      = (const float*)d_in[1];
    const float* attn_l = (const float*)d_in[2];
    const float* attn_r = (const float*)d_in[3];
    const int*   src    = (const int*)d_in[4];
    const int*   dst    = (const int*)d_in[5];
    float* out = (float*)d_out;

    // workspace (~45 MB): h2 has a dummy row; ssrc has padding + prefetch slack
    f16*   h2    = (f16*)d_ws;                                 // (N+8)*128 f16
    float* el    = (float*)(h2 + (size_t)(N_NODES + 8) * 128); // (N+4)*4
    float* er    = el + (size_t)(N_NODES + 4) * 4;             // N*4
    int*   deg   = (int*)(er + (size_t)N_NODES * 4);           // N
    int*   start = deg + N_NODES;                              // N
    int*   rank  = start + N_NODES;                            // E
    int*   ssrc  = rank + E_EDGES;                             // E + 3N (padded)
    int*   aux   = ssrc + E_EDGES + 3 * N_NODES + 64;          // 128

    hipMemsetAsync(deg, 0, N_NODES * sizeof(int), stream);

    k_gemm_hist<<<NBLOCKS, 256, 0, stream>>>(feat, W, attn_l, attn_r, h2, el, er,
                                             (const int4*)dst, deg, (int4*)rank);
    k_bsum<<<NBLK, 256, 0, stream>>>(deg, aux);
    k_bscan<<<NBLK, 256, 0, stream>>>(deg, aux, start, ssrc, h2, el);
    k_scatter<<<(E_EDGES / 4 + 255) / 256, 256, 0, stream>>>(
        (const int4*)src, (const int4*)dst, (const int4*)rank, start, ssrc);
    k_aggr<<<(N_NODES + 1) / 2, 128, 0, stream>>>(h2, el, er, ssrc, start, deg, out);
}